// Round 1
// baseline (1338.199 us; speedup 1.0000x reference)
//
#include <hip/hip_runtime.h>
#include <cstdint>
#include <cstddef>

typedef __bf16 bf16_t;
typedef __attribute__((ext_vector_type(8))) __bf16 bf16x8;
typedef __attribute__((ext_vector_type(4))) __bf16 bf16x4;
typedef __attribute__((ext_vector_type(4))) float floatx4;

// ---------------------------------------------------------------------------
// async 16B global -> LDS copy (direct-to-LDS DMA, no VGPR round trip).
// LDS dest must be wave-uniform base + lane*16 — our layouts guarantee this.
__device__ __forceinline__ void cp16(const void* g, void* l) {
  __builtin_amdgcn_global_load_lds(
      (const __attribute__((address_space(1))) void*)(uintptr_t)g,
      (__attribute__((address_space(3))) void*)(uintptr_t)l, 16, 0, 0);
}

// ---------------------------------------------------------------------------
// x fp32 -> bf16 (vectorized)
__global__ void cvt_to_bf16(const float4* __restrict__ in,
                            bf16x4* __restrict__ out, int n4) {
  int i = blockIdx.x * 256 + threadIdx.x;
  if (i < n4) {
    float4 f = in[i];
    bf16x4 o;
    o[0] = (bf16_t)f.x; o[1] = (bf16_t)f.y; o[2] = (bf16_t)f.z; o[3] = (bf16_t)f.w;
    out[i] = o;
  }
}

// ---------------------------------------------------------------------------
// W^T assembly: Wt[n][k] = bf16(M[k][n] + exp(.5u[k]) * eps[k][n] * exp(.5v[n]))
// for k in [0,K), n in [0,N). (Row K of M/eps is the bias row, handled below.)
// 32x32 LDS tile transpose, block (32,8).
__global__ void prep_wt(const float* __restrict__ M, const float* __restrict__ u,
                        const float* __restrict__ v, const float* __restrict__ eps,
                        bf16_t* __restrict__ Wt, int K, int N) {
  __shared__ float tile[32][33];  // +1 pad: conflict-free transposed read
  const int nb = blockIdx.x * 32, kb = blockIdx.y * 32;
  const int tx = threadIdx.x, ty = threadIdx.y;
  const float sv = __expf(0.5f * v[nb + tx]);
#pragma unroll
  for (int r = 0; r < 4; ++r) {
    const int k = kb + ty + 8 * r;
    const float su = __expf(0.5f * u[k]);
    const size_t idx = (size_t)k * N + nb + tx;
    tile[ty + 8 * r][tx] = M[idx] + su * eps[idx] * sv;
  }
  __syncthreads();
#pragma unroll
  for (int r = 0; r < 4; ++r) {
    const int n = nb + ty + 8 * r;
    Wt[(size_t)n * K + kb + tx] = (bf16_t)tile[tx][ty + 8 * r];
  }
}

// bias[n] = M[K][n] + exp(.5u[K]) * eps[K][n] * exp(.5v[n])   (fp32)
__global__ void prep_bias(const float* __restrict__ M, const float* __restrict__ u,
                          const float* __restrict__ v, const float* __restrict__ eps,
                          float* __restrict__ bias, int K, int N) {
  int n = blockIdx.x * 256 + threadIdx.x;
  if (n < N) {
    const size_t idx = (size_t)K * N + n;
    bias[n] = M[idx] + __expf(0.5f * u[K]) * eps[idx] * __expf(0.5f * v[n]);
  }
}

// ---------------------------------------------------------------------------
// bf16 GEMM, m97 structure: C[8192,N] = A[8192,K] @ Bt[N,K]^T + bias
// 128x128 block tile, BK=32, 4 waves in 2x2, each wave 4x4 of 16x16x32 MFMA.
// EPI==0: C = bf16(relu(acc+bias));  EPI==1: C = fp32(acc+bias)
template <int EPI>
__global__ __launch_bounds__(256, 2) void gemm_bt(
    const bf16_t* __restrict__ A, const bf16_t* __restrict__ Bt,
    const float* __restrict__ bias, void* __restrict__ Cout, int N, int K) {
  __shared__ bf16_t As[128 * 32];  // [row][k], row-major, k contiguous (8 KB)
  __shared__ bf16_t Bs[128 * 32];  // [nrow][k]

  const int tid = threadIdx.x;
  const int lane = tid & 63;
  const int wave = tid >> 6;
  const int wm = (wave >> 1) * 64;
  const int wn = (wave & 1) * 64;
  const int bm = blockIdx.y * 128;
  const int bn = blockIdx.x * 128;

  // staging: thread t covers row = t>>2 (+64 for 2nd issue), 8 bf16 at col (t&3)*8
  const int srow = tid >> 2;
  const int scol = (tid & 3) * 8;
  const bf16_t* aG0 = A + (size_t)(bm + srow) * K + scol;
  const bf16_t* aG1 = aG0 + (size_t)64 * K;
  const bf16_t* bG0 = Bt + (size_t)(bn + srow) * K + scol;
  const bf16_t* bG1 = bG0 + (size_t)64 * K;
  char* aL0 = (char*)As + tid * 16;  // linear: byte off = tid*16 (wave base + lane*16)
  char* aL1 = aL0 + 4096;
  char* bL0 = (char*)Bs + tid * 16;
  char* bL1 = bL0 + 4096;

  floatx4 acc[4][4] = {};

  const int mRow = wm + (lane & 15);
  const int nRow = wn + (lane & 15);
  const int kq = lane >> 4;  // k-quad: elements kq*8 .. kq*8+7

  for (int k0 = 0; k0 < K; k0 += 32) {
    cp16(aG0 + k0, aL0);
    cp16(aG1 + k0, aL1);
    cp16(bG0 + k0, bL0);
    cp16(bG1 + k0, bL1);
    __syncthreads();  // compiler emits vmcnt(0) drain before barrier

    const bf16x8* As8 = (const bf16x8*)As;
    const bf16x8* Bs8 = (const bf16x8*)Bs;
    bf16x8 af[4], bfr[4];
#pragma unroll
    for (int i = 0; i < 4; ++i) af[i] = As8[(mRow + i * 16) * 4 + kq];
#pragma unroll
    for (int j = 0; j < 4; ++j) bfr[j] = Bs8[(nRow + j * 16) * 4 + kq];
#pragma unroll
    for (int i = 0; i < 4; ++i)
#pragma unroll
      for (int j = 0; j < 4; ++j)
        acc[i][j] = __builtin_amdgcn_mfma_f32_16x16x32_bf16(af[i], bfr[j],
                                                            acc[i][j], 0, 0, 0);
    __syncthreads();
  }

  // epilogue: C/D layout col = lane&15, row = (lane>>4)*4 + reg  [m89-verified]
  const int col = bn + wn + (lane & 15);
  const int row0 = bm + wm + kq * 4;
#pragma unroll
  for (int j = 0; j < 4; ++j) {
    const float bj = bias[col + j * 16];
#pragma unroll
    for (int i = 0; i < 4; ++i) {
#pragma unroll
      for (int r = 0; r < 4; ++r) {
        float v = acc[i][j][r] + bj;
        const size_t idx = (size_t)(row0 + i * 16 + r) * N + (col + j * 16);
        if (EPI == 0) {
          v = v > 0.f ? v : 0.f;
          ((bf16_t*)Cout)[idx] = (bf16_t)v;
        } else {
          ((float*)Cout)[idx] = v;
        }
      }
    }
  }
}

// ---------------------------------------------------------------------------
extern "C" void kernel_launch(void* const* d_in, const int* in_sizes, int n_in,
                              void* d_out, int out_size, void* d_ws, size_t ws_size,
                              hipStream_t stream) {
  const float* x = (const float*)d_in[0];
  const float *Mm[4], *uu[4], *vv[4], *ee[4];
  for (int i = 0; i < 4; ++i) {
    Mm[i] = (const float*)d_in[1 + 4 * i];
    uu[i] = (const float*)d_in[2 + 4 * i];
    vv[i] = (const float*)d_in[3 + 4 * i];
    ee[i] = (const float*)d_in[4 + 4 * i];
  }

  // workspace layout (≈224 MiB):
  //   Wt0 [4096,2048] bf16 | Wt1 [4096,4096] | Wt2 [4096,4096] | Wt3 [2048,4096]
  //   bias0..3 fp32 | hA (8192x4096 bf16) | hB (8192x4096 bf16)
  // x_bf16 lives in d_out (dead until final GEMM overwrites all of d_out).
  char* ws = (char*)d_ws;
  bf16_t* Wt0 = (bf16_t*)ws;                                   // 16,777,216 B
  bf16_t* Wt1 = (bf16_t*)(ws + 16777216);                      // 33,554,432 B
  bf16_t* Wt2 = (bf16_t*)(ws + 16777216 + 33554432);           // 33,554,432 B
  bf16_t* Wt3 = (bf16_t*)(ws + 16777216 + 2u * 33554432);      // 16,777,216 B
  char* bptr = ws + 2u * 16777216 + 2u * 33554432;             // = 100,663,296
  float* bias0 = (float*)(bptr);
  float* bias1 = (float*)(bptr + 16384);
  float* bias2 = (float*)(bptr + 32768);
  float* bias3 = (float*)(bptr + 49152);
  char* act = bptr + 65536;
  bf16_t* hA = (bf16_t*)act;                // 67,108,864 B (h0, then h2)
  bf16_t* hB = (bf16_t*)(act + 67108864);   // 67,108,864 B (h1)
  bf16_t* xb = (bf16_t*)d_out;              // 33,554,432 B of d_out's 67 MB

  // --- prep ---
  cvt_to_bf16<<<16384, 256, 0, stream>>>((const float4*)x, (bf16x4*)xb,
                                         8192 * 2048 / 4);
  prep_wt<<<dim3(4096 / 32, 2048 / 32), dim3(32, 8), 0, stream>>>(
      Mm[0], uu[0], vv[0], ee[0], Wt0, 2048, 4096);
  prep_wt<<<dim3(4096 / 32, 4096 / 32), dim3(32, 8), 0, stream>>>(
      Mm[1], uu[1], vv[1], ee[1], Wt1, 4096, 4096);
  prep_wt<<<dim3(4096 / 32, 4096 / 32), dim3(32, 8), 0, stream>>>(
      Mm[2], uu[2], vv[2], ee[2], Wt2, 4096, 4096);
  prep_wt<<<dim3(2048 / 32, 4096 / 32), dim3(32, 8), 0, stream>>>(
      Mm[3], uu[3], vv[3], ee[3], Wt3, 4096, 2048);
  prep_bias<<<16, 256, 0, stream>>>(Mm[0], uu[0], vv[0], ee[0], bias0, 2048, 4096);
  prep_bias<<<16, 256, 0, stream>>>(Mm[1], uu[1], vv[1], ee[1], bias1, 4096, 4096);
  prep_bias<<<16, 256, 0, stream>>>(Mm[2], uu[2], vv[2], ee[2], bias2, 4096, 4096);
  prep_bias<<<8, 256, 0, stream>>>(Mm[3], uu[3], vv[3], ee[3], bias3, 4096, 2048);

  // --- chained GEMMs ---
  gemm_bt<0><<<dim3(32, 64), 256, 0, stream>>>(xb, Wt0, bias0, hA, 4096, 2048);
  gemm_bt<0><<<dim3(32, 64), 256, 0, stream>>>(hA, Wt1, bias1, hB, 4096, 4096);
  gemm_bt<0><<<dim3(32, 64), 256, 0, stream>>>(hB, Wt2, bias2, hA, 4096, 4096);
  gemm_bt<1><<<dim3(16, 64), 256, 0, stream>>>(hA, Wt3, bias3, d_out, 2048, 4096);
}